// Round 8
// baseline (51.946 us; speedup 1.0000x reference)
//
#include <hip/hip_runtime.h>
#include <stdint.h>

#define BATCH  262144
#define HIST   100
#define HIDDEN 128

typedef __attribute__((ext_vector_type(8))) short short8_t;  // 8 bf16
typedef __attribute__((ext_vector_type(4))) float f32x4;

__device__ __forceinline__ uint32_t cvt_pk_bf16(float lo, float hi) {
    uint32_t d;
    asm("v_cvt_pk_bf16_f32 %0, %1, %2" : "=v"(d) : "v"(lo), "v"(hi));
    return d;   // d[15:0]=bf16(lo), d[31:16]=bf16(hi)
}

union FragU { uint32_t u[4]; short8_t s8; uint4 u4; };

#define VMCNT0 asm volatile("s_waitcnt vmcnt(0)" ::: "memory")
#define SBAR   __builtin_amdgcn_sched_barrier(0)

// ONE WAVE per block, 64 rows. Streaming via global_load_lds: each
// instruction reads 1024 CONTIGUOUS bytes (copy-class DRAM pattern,
// max row-buffer hits) into a linear 25.6KB LDS tile; 2 stages x 32 rows.
// Features read back 2-lanes-per-row from LDS (all window predicates
// compile-time), pair shfl reduce, in-wave redistribute. MLP phase
// (layer1 VALU + bf16 pack + MFMA layer2 + epilogue) identical to r7.
// No __syncthreads anywhere (wave-local LDS, explicit vmcnt fences).
__global__ __launch_bounds__(64) void competence_kernel(
    const float* __restrict__ hist,
    const float* __restrict__ W1, const float* __restrict__ b1,
    const float* __restrict__ W2, const float* __restrict__ b2,
    const float* __restrict__ W3, const float* __restrict__ b3,
    float* __restrict__ out)
{
    __shared__ float4   tile[1600];   // 25.6 KB: 32 rows x 50 float4, linear
    __shared__ uint32_t h1t[2048];    // 8 KB: 64 rows x 32 dw, XOR-swizzled

    const int lane = threadIdx.x;     // 0..63
    const int rloc = lane >> 1;       // local row 0..31 (2 lanes per row)
    const int q    = lane & 1;        // odd/even float4 phase
    const float4* __restrict__ hist4 = (const float4*)hist;
    const size_t slab = (size_t)blockIdx.x * 3200;   // 64 rows x 50 f4

    float sumS[2], rmeS[2], maxS[2];

    #pragma unroll
    for (int s = 0; s < 2; ++s) {
        // ---- stage s: 25 x 1KB contiguous global -> linear LDS ----
        #pragma unroll
        for (int i = 0; i < 25; ++i) {
            const float4* src = hist4 + slab + s * 1600 + i * 64 + lane;
            __builtin_amdgcn_global_load_lds(
                (const __attribute__((address_space(1))) void*)src,
                (__attribute__((address_space(3))) void*)&tile[i * 64],
                16, 0, 0);
        }
        VMCNT0; SBAR;

        // ---- consume: pair (2r,2r+1) processes row r; lane reads f4
        //      indices {2c+q} -> early: c<5 (idx<10), recent: c>=20 ----
        float sum = 0.f, early = 0.f, recent = 0.f, maxd = 0.f;
        #pragma unroll
        for (int c = 0; c < 25; ++c) {
            float4 v = tile[rloc * 50 + 2 * c + q];
            float s2 = v.x + v.z;
            sum += s2;
            if (c < 5)   early  += s2;
            if (c >= 20) recent += s2;
            maxd = fmaxf(maxd, v.x > 0.5f ? v.y : 0.0f);
            maxd = fmaxf(maxd, v.z > 0.5f ? v.w : 0.0f);
        }
        float rme = recent - early;
        sum += __shfl_xor(sum, 1);
        rme += __shfl_xor(rme, 1);
        maxd = fmaxf(maxd, __shfl_xor(maxd, 1));
        sumS[s] = sum; rmeS[s] = rme; maxS[s] = maxd;
        SBAR;   // next stage's loads must not hoist above these ds_reads
    }

    // ---- redistribute: row x lives at lane 2*(x&31), stage x>>5 ----
    const int src = (lane & 31) << 1;
    float sA = __shfl(sumS[0], src), sB = __shfl(sumS[1], src);
    float rA = __shfl(rmeS[0], src), rB = __shfl(rmeS[1], src);
    float mA = __shfl(maxS[0], src), mB = __shfl(maxS[1], src);
    const bool hi = lane >= 32;
    const float f0 = (hi ? sB : sA) * 0.01f;
    const float f1 = (hi ? rB : rA) * 0.05f;
    const float f2 =  hi ? mB : mA;

    // ---------------- B fragments (W2 -> bf16) + per-lane b2/W3 slices -----
    const int cl = lane & 15;
    const int ko = lane >> 4;
    const float b2v0 = b2[cl],  b2v1 = b2[16 + cl];
    const float w3v0 = W3[cl],  w3v1 = W3[16 + cl];
    const float b3v  = b3[0];

    short8_t bfr[8];                             // [kstep s][ntile n] = s*2+n
    #pragma unroll
    for (int s = 0; s < 4; ++s) {
        #pragma unroll
        for (int n = 0; n < 2; ++n) {
            float wv[8];
            #pragma unroll
            for (int i = 0; i < 8; ++i)          // k = 32s + 8*ko + i
                wv[i] = W2[(32 * s + 8 * ko + i) * 32 + n * 16 + cl];
            FragU fu;
            #pragma unroll
            for (int p = 0; p < 4; ++p)
                fu.u[p] = cvt_pk_bf16(wv[2 * p], wv[2 * p + 1]);
            bfr[s * 2 + n] = fu.s8;
        }
    }

    f32x4 acc[4][2];
    #pragma unroll
    for (int g = 0; g < 4; ++g)
        #pragma unroll
        for (int n = 0; n < 2; ++n)
            acc[g][n] = (f32x4){0.f, 0.f, 0.f, 0.f};

    const int r = lane;

    #pragma unroll
    for (int hh = 0; hh < 2; ++hh) {             // K halves: j in [64hh,64hh+64)
        // ---- layer 1 for this half: compute, pack, swizzled LDS write ----
        #pragma unroll
        for (int j8 = 0; j8 < 8; ++j8) {
            FragU pk;
            #pragma unroll
            for (int p = 0; p < 4; ++p) {
                const int j = hh * 64 + j8 * 8 + p * 2;
                float h0 = fmaf(f2, W1[256 + j],
                            fmaf(f1, W1[128 + j], fmaf(f0, W1[j], b1[j])));
                float h1 = fmaf(f2, W1[256 + j + 1],
                            fmaf(f1, W1[128 + j + 1],
                                 fmaf(f0, W1[j + 1], b1[j + 1])));
                pk.u[p] = cvt_pk_bf16(fmaxf(h0, 0.f), fmaxf(h1, 0.f));
            }
            *(uint4*)&h1t[r * 32 + ((j8 ^ (r & 7)) << 2)] = pk.u4;
        }
        // ---- MFMA for this half (wave-local LDS, no barrier needed) ----
        #pragma unroll
        for (int g = 0; g < 4; ++g) {
            const int arow = g * 16 + cl;
            #pragma unroll
            for (int sp = 0; sp < 2; ++sp) {
                const int j8r = sp * 4 + ko;
                short8_t a = *(const short8_t*)
                    &h1t[arow * 32 + ((j8r ^ (arow & 7)) << 2)];
                const int s = hh * 2 + sp;
                acc[g][0] = __builtin_amdgcn_mfma_f32_16x16x32_bf16(
                    a, bfr[s * 2 + 0], acc[g][0], 0, 0, 0);
                acc[g][1] = __builtin_amdgcn_mfma_f32_16x16x32_bf16(
                    a, bfr[s * 2 + 1], acc[g][1], 0, 0, 0);
            }
        }
    }

    // ---------------- epilogue ----------------
    #pragma unroll
    for (int g = 0; g < 4; ++g) {
        float o[4];
        #pragma unroll
        for (int p = 0; p < 4; ++p) {
            float v0 = fmaxf(acc[g][0][p] + b2v0, 0.f) * w3v0;
            float v1 = fmaxf(acc[g][1][p] + b2v1, 0.f) * w3v1;
            o[p] = v0 + v1;
        }
        #pragma unroll
        for (int m = 1; m < 16; m <<= 1)
            #pragma unroll
            for (int p = 0; p < 4; ++p)
                o[p] += __shfl_xor(o[p], m);
        if (cl == 0) {
            float4 res;
            res.x = 1.f / (1.f + __expf(-(o[0] + b3v)));
            res.y = 1.f / (1.f + __expf(-(o[1] + b3v)));
            res.z = 1.f / (1.f + __expf(-(o[2] + b3v)));
            res.w = 1.f / (1.f + __expf(-(o[3] + b3v)));
            *(float4*)&out[blockIdx.x * 64 + g * 16 + ko * 4] = res;
        }
    }
}

extern "C" void kernel_launch(void* const* d_in, const int* in_sizes, int n_in,
                              void* d_out, int out_size, void* d_ws, size_t ws_size,
                              hipStream_t stream) {
    const float* hist = (const float*)d_in[0];
    const float* W1   = (const float*)d_in[1];
    const float* b1   = (const float*)d_in[2];
    const float* W2   = (const float*)d_in[3];
    const float* b2   = (const float*)d_in[4];
    const float* W3   = (const float*)d_in[5];
    const float* b3   = (const float*)d_in[6];
    float* out = (float*)d_out;

    const int threads = 64;            // one wave per block
    const int blocks  = BATCH / 64;    // 4096 blocks
    competence_kernel<<<blocks, threads, 0, stream>>>(
        hist, W1, b1, W2, b2, W3, b3, out);
}

// Round 9
// 46.756 us; speedup vs baseline: 1.1110x; 1.1110x over previous
//
#include <hip/hip_runtime.h>
#include <stdint.h>

#define BATCH  262144
#define HIST   100
#define HIDDEN 128

typedef __attribute__((ext_vector_type(8))) short short8_t;  // 8 bf16
typedef __attribute__((ext_vector_type(4))) float f32x4;

__device__ __forceinline__ uint32_t cvt_pk_bf16(float lo, float hi) {
    uint32_t d;
    asm("v_cvt_pk_bf16_f32 %0, %1, %2" : "=v"(d) : "v"(lo), "v"(hi));
    return d;   // d[15:0]=bf16(lo), d[31:16]=bf16(hi)
}

union FragU { uint32_t u[4]; short8_t s8; uint4 u4; };

// ============================ Kernel A: features =========================
// Pure streaming, tiny VGPR footprint -> high occupancy (target 24-32
// waves/CU, 2x the fused kernel) for load-latency hiding. 4 lanes per row
// (full-line coalescing), compile-time windows, 4-lane butterfly, q==0
// writes float4{f0,f1,f2,0} per row to d_ws.
__global__ __launch_bounds__(256) void feat_kernel(
    const float* __restrict__ hist, float4* __restrict__ feat)
{
    const int tid = blockIdx.x * 256 + threadIdx.x;
    const int q   = tid & 3;            // float4-phase within row
    const size_t row = (size_t)(tid >> 2);

    const float4* __restrict__ h4 = (const float4*)(hist + row * (HIST * 2));

    float sum = 0.f, early = 0.f, recent = 0.f, maxd = 0.f;
    #pragma unroll
    for (int i = 0; i < 12; ++i) {      // float4 idx = 4i+q in [0,48)
        float4 v = h4[4 * i + q];
        float s2 = v.x + v.z;
        sum += s2;
        if (i < 2)       early += s2;                    // idx 0..7
        else if (i == 2) early += (q < 2) ? s2 : 0.f;    // idx 8,9 only
        if (i >= 10)     recent += s2;                   // idx 40..47
        maxd = fmaxf(maxd, v.x > 0.5f ? v.y : 0.0f);
        maxd = fmaxf(maxd, v.z > 0.5f ? v.w : 0.0f);
    }
    if (q < 2) {                        // tail: float4 idx 48,49
        float4 v = h4[48 + q];
        float s2 = v.x + v.z;
        sum += s2; recent += s2;
        maxd = fmaxf(maxd, v.x > 0.5f ? v.y : 0.0f);
        maxd = fmaxf(maxd, v.z > 0.5f ? v.w : 0.0f);
    }
    float rme = recent - early;
    #pragma unroll
    for (int m = 1; m < 4; m <<= 1) {
        sum += __shfl_xor(sum, m);
        rme += __shfl_xor(rme, m);
        maxd = fmaxf(maxd, __shfl_xor(maxd, m));
    }
    if (q == 0)
        feat[row] = make_float4(sum * 0.01f, rme * 0.05f, maxd, 0.f);
}

// ============================ Kernel B: MLP ==============================
// r7's proven phases 2-4 verbatim; features loaded coalesced (1KB/wave).
__global__ __launch_bounds__(64) void mlp_kernel(
    const float4* __restrict__ feat,
    const float* __restrict__ W1, const float* __restrict__ b1,
    const float* __restrict__ W2, const float* __restrict__ b2,
    const float* __restrict__ W3, const float* __restrict__ b3,
    float* __restrict__ out)
{
    __shared__ uint32_t h1t[2048];      // 8 KB: 64 rows x 32 dw, XOR-swizzled

    const int lane = threadIdx.x;       // 0..63
    const size_t row0 = (size_t)blockIdx.x * 64;

    const float4 F = feat[row0 + lane];
    const float f0 = F.x, f1 = F.y, f2 = F.z;

    const int cl = lane & 15;
    const int ko = lane >> 4;
    const float b2v0 = b2[cl],  b2v1 = b2[16 + cl];
    const float w3v0 = W3[cl],  w3v1 = W3[16 + cl];
    const float b3v  = b3[0];

    short8_t bfr[8];                    // [kstep s][ntile n] = s*2+n
    #pragma unroll
    for (int s = 0; s < 4; ++s) {
        #pragma unroll
        for (int n = 0; n < 2; ++n) {
            float wv[8];
            #pragma unroll
            for (int i = 0; i < 8; ++i)          // k = 32s + 8*ko + i
                wv[i] = W2[(32 * s + 8 * ko + i) * 32 + n * 16 + cl];
            FragU fu;
            #pragma unroll
            for (int p = 0; p < 4; ++p)
                fu.u[p] = cvt_pk_bf16(wv[2 * p], wv[2 * p + 1]);
            bfr[s * 2 + n] = fu.s8;
        }
    }

    f32x4 acc[4][2];
    #pragma unroll
    for (int g = 0; g < 4; ++g)
        #pragma unroll
        for (int n = 0; n < 2; ++n)
            acc[g][n] = (f32x4){0.f, 0.f, 0.f, 0.f};

    const int r = lane;

    #pragma unroll
    for (int hh = 0; hh < 2; ++hh) {    // K halves: j in [64hh, 64hh+64)
        #pragma unroll
        for (int j8 = 0; j8 < 8; ++j8) {
            FragU pk;
            #pragma unroll
            for (int p = 0; p < 4; ++p) {
                const int j = hh * 64 + j8 * 8 + p * 2;
                float h0 = fmaf(f2, W1[256 + j],
                            fmaf(f1, W1[128 + j], fmaf(f0, W1[j], b1[j])));
                float h1 = fmaf(f2, W1[256 + j + 1],
                            fmaf(f1, W1[128 + j + 1],
                                 fmaf(f0, W1[j + 1], b1[j + 1])));
                pk.u[p] = cvt_pk_bf16(fmaxf(h0, 0.f), fmaxf(h1, 0.f));
            }
            *(uint4*)&h1t[r * 32 + ((j8 ^ (r & 7)) << 2)] = pk.u4;
        }
        #pragma unroll
        for (int g = 0; g < 4; ++g) {
            const int arow = g * 16 + cl;
            #pragma unroll
            for (int sp = 0; sp < 2; ++sp) {
                const int j8r = sp * 4 + ko;
                short8_t a = *(const short8_t*)
                    &h1t[arow * 32 + ((j8r ^ (arow & 7)) << 2)];
                const int s = hh * 2 + sp;
                acc[g][0] = __builtin_amdgcn_mfma_f32_16x16x32_bf16(
                    a, bfr[s * 2 + 0], acc[g][0], 0, 0, 0);
                acc[g][1] = __builtin_amdgcn_mfma_f32_16x16x32_bf16(
                    a, bfr[s * 2 + 1], acc[g][1], 0, 0, 0);
            }
        }
    }

    #pragma unroll
    for (int g = 0; g < 4; ++g) {
        float o[4];
        #pragma unroll
        for (int p = 0; p < 4; ++p) {
            float v0 = fmaxf(acc[g][0][p] + b2v0, 0.f) * w3v0;
            float v1 = fmaxf(acc[g][1][p] + b2v1, 0.f) * w3v1;
            o[p] = v0 + v1;
        }
        #pragma unroll
        for (int m = 1; m < 16; m <<= 1)
            #pragma unroll
            for (int p = 0; p < 4; ++p)
                o[p] += __shfl_xor(o[p], m);
        if (cl == 0) {
            float4 res;
            res.x = 1.f / (1.f + __expf(-(o[0] + b3v)));
            res.y = 1.f / (1.f + __expf(-(o[1] + b3v)));
            res.z = 1.f / (1.f + __expf(-(o[2] + b3v)));
            res.w = 1.f / (1.f + __expf(-(o[3] + b3v)));
            *(float4*)&out[blockIdx.x * 64 + g * 16 + ko * 4] = res;
        }
    }
}

extern "C" void kernel_launch(void* const* d_in, const int* in_sizes, int n_in,
                              void* d_out, int out_size, void* d_ws, size_t ws_size,
                              hipStream_t stream) {
    const float* hist = (const float*)d_in[0];
    const float* W1   = (const float*)d_in[1];
    const float* b1   = (const float*)d_in[2];
    const float* W2   = (const float*)d_in[3];
    const float* b2   = (const float*)d_in[4];
    const float* W3   = (const float*)d_in[5];
    const float* b3   = (const float*)d_in[6];
    float* out   = (float*)d_out;
    float4* feat = (float4*)d_ws;       // 262144 x 16 B = 4 MB scratch

    // Kernel A: features (BATCH*4 lanes / 256 = 4096 blocks)
    feat_kernel<<<BATCH * 4 / 256, 256, 0, stream>>>(hist, feat);
    // Kernel B: MLP (same stream -> ordered after A)
    mlp_kernel<<<BATCH / 64, 64, 0, stream>>>(
        (const float4*)feat, W1, b1, W2, b2, W3, b3, out);
}